// Round 4
// baseline (8563.616 us; speedup 1.0000x reference)
//
#include <hip/hip_runtime.h>
#include <cstdint>

// ---------------------------------------------------------------------------
// LorentzMLA on MI355X (gfx950). R9: DIAGNOSTIC DUAL-PATH round.
// Pipeline = R5 verbatim (passed @8340us): attn_f32 -> centb -> final gemm.
// Additionally launches the new MFMA-attention machinery (kb_build, vb_build,
// attn_mfma) writing ONLY into the dead region at offC (33.5MB: W0b + offD
// weights/kvfull, all consumed by then; W3b pad_convert overwrites after).
// Their outputs are never consumed -> correctness unaffected; their dispatches
// appear in rocprof -> tells us whether they launch and how fast they run.
// ---------------------------------------------------------------------------

typedef unsigned short u16;
typedef __bf16 bf16x8 __attribute__((ext_vector_type(8)));
typedef float f32x4 __attribute__((ext_vector_type(4)));

#define DEV __device__ __forceinline__

DEV u16 f2bf(float f) {
  unsigned u = __builtin_bit_cast(unsigned, f);
  u = u + 0x7fffu + ((u >> 16) & 1u);
  return (u16)(u >> 16);
}

DEV void async16(void* lds, const void* g) {
  __builtin_amdgcn_global_load_lds(
      (__attribute__((address_space(1))) void*)(uintptr_t)g,
      (__attribute__((address_space(3))) void*)lds, 16, 0, 0);
}

DEV float wred_sum(float v) {
  v += __shfl_xor(v, 1);  v += __shfl_xor(v, 2);  v += __shfl_xor(v, 4);
  v += __shfl_xor(v, 8);  v += __shfl_xor(v, 16); v += __shfl_xor(v, 32);
  return v;
}

DEV bf16x8 cvt8(f32x4 a, f32x4 b) {
  union { bf16x8 v; u16 u[8]; } r;
#pragma unroll
  for (int i = 0; i < 4; i++) { r.u[i] = f2bf(a[i]); r.u[4 + i] = f2bf(b[i]); }
  return r.v;
}

// ---------------------------------------------------------------------------
// fp32 -> bf16 with zero padding. dst (rd x cd), src (rs x cs).
// ---------------------------------------------------------------------------
__global__ __launch_bounds__(256)
void pad_convert(const float* __restrict__ src, u16* __restrict__ dst,
                 int rs, int cs, int cd, int total) {
  int idx = blockIdx.x * 256 + threadIdx.x;
  if (idx >= total) return;
  int r = idx / cd, c = idx - r * cd;
  float v = (r < rs && c < cs) ? src[(size_t)r * cs + c] : 0.f;
  dst[idx] = f2bf(v);
}

// ---------------------------------------------------------------------------
// out[m][n] = sum_k A[m][k]*W[n][k] + bias[n].  A: MxK bf16, W: NxK bf16.
// 128x128 tile, BK=32, 16x16x32 MFMA, global_load_lds(16B) staging. fp32 out.
// ---------------------------------------------------------------------------
__global__ __launch_bounds__(256)
void gemm_bt(const u16* __restrict__ A, const u16* __restrict__ W,
             const float* __restrict__ bias, float* __restrict__ outF,
             int K, int ldo, int nstore) {
  __shared__ __align__(16) u16 As[128 * 32];
  __shared__ __align__(16) u16 Bs[128 * 32];
  const int tid = threadIdx.x;
  const int w = tid >> 6, lane = tid & 63;
  const int quad = lane >> 4, l16 = lane & 15;
  const int bm = blockIdx.y * 128, bn = blockIdx.x * 128;
  const int wm = (w & 1) * 64, wn = (w >> 1) * 64;
  const int sr = lane >> 2;
  const int sc = (lane & 3) * 8;

  f32x4 acc[4][4];
#pragma unroll
  for (int i = 0; i < 4; i++)
#pragma unroll
    for (int j = 0; j < 4; j++) acc[i][j] = (f32x4){0.f, 0.f, 0.f, 0.f};

  const u16* Ab = A + (size_t)bm * K;
  const u16* Wb = W + (size_t)bn * K;

  for (int k0 = 0; k0 < K; k0 += 32) {
    __syncthreads();
#pragma unroll
    for (int i = 0; i < 2; ++i) {
      int rr = w * 32 + i * 16;
      async16((char*)&As[rr * 32] + (size_t)lane * 16,
              Ab + (size_t)(rr + sr) * K + k0 + sc);
      async16((char*)&Bs[rr * 32] + (size_t)lane * 16,
              Wb + (size_t)(rr + sr) * K + k0 + sc);
    }
    __syncthreads();
    bf16x8 aF[4], bF[4];
#pragma unroll
    for (int i = 0; i < 4; i++)
      aF[i] = *(const bf16x8*)&As[(wm + i * 16 + l16) * 32 + quad * 8];
#pragma unroll
    for (int i = 0; i < 4; i++)
      bF[i] = *(const bf16x8*)&Bs[(wn + i * 16 + l16) * 32 + quad * 8];
#pragma unroll
    for (int im = 0; im < 4; im++)
#pragma unroll
      for (int in = 0; in < 4; in++)
        acc[im][in] = __builtin_amdgcn_mfma_f32_16x16x32_bf16(
            aF[im], bF[in], acc[im][in], 0, 0, 0);
  }

#pragma unroll
  for (int im = 0; im < 4; im++) {
#pragma unroll
    for (int in = 0; in < 4; in++) {
      int gn = bn + wn + in * 16 + l16;
      if (gn >= nstore) continue;
      float bv = bias[gn];
#pragma unroll
      for (int j = 0; j < 4; j++) {
        int gm = bm + wm + im * 16 + quad * 4 + j;
        outF[(size_t)gm * ldo + gn] = acc[im][in][j] + bv;
      }
    }
  }
}

// ---------------------------------------------------------------------------
// qpre (4096 x 3072 f32) -> qhat (65536 x 192 f32) + QT.
// ---------------------------------------------------------------------------
__global__ __launch_bounds__(256)
void q_assemble_f32(const float* __restrict__ qpre, const float* __restrict__ fcos,
                    const float* __restrict__ fsin, float* __restrict__ qhat,
                    float* __restrict__ QT) {
  int row = blockIdx.x * 4 + (threadIdx.x >> 6);   // = bh*1024 + s
  int lane = threadIdx.x & 63;
  int b = row >> 14, h = (row >> 10) & 15, s = row & 1023;
  const float* src = qpre + (size_t)(b * 1024 + s) * 3072 + h * 192;
  float e0 = src[2 * lane], e1 = src[2 * lane + 1];
  float y1 = 0.f, y2 = 0.f;
  float sq = e0 * e0 + e1 * e1;
  if (lane < 32) {
    float x1 = src[128 + 2 * lane], x2 = src[128 + 2 * lane + 1];
    float c = fcos[s * 32 + lane], sn = fsin[s * 32 + lane];
    y1 = x1 * c - x2 * sn;
    y2 = x1 * sn + x2 * c;
    sq += x1 * x1 + x2 * x2;
  }
  sq = wred_sum(sq);
  float* dst = qhat + (size_t)row * 192;
  dst[2 * lane] = e0;
  dst[2 * lane + 1] = e1;
  if (lane < 32) { dst[128 + 2 * lane] = y1; dst[128 + 2 * lane + 1] = y2; }
  if (lane == 0) QT[row] = sqrtf(sq + 1.0f);
}

// ---------------------------------------------------------------------------
// kvfull (4096 x 576 f32) -> kvnb (4096 x 544 bf16: [t, sp512, 31 zeros])
// + kpe (4096 x 64 f32).
// ---------------------------------------------------------------------------
__global__ __launch_bounds__(256)
void kv_assemble1_f32(const float* __restrict__ kvfull, const float* __restrict__ wnorm,
                      const float* __restrict__ fcos, const float* __restrict__ fsin,
                      u16* __restrict__ kvnb, float* __restrict__ kpe) {
  int row = blockIdx.x * 4 + (threadIdx.x >> 6);   // b*1024 + s
  int lane = threadIdx.x & 63;
  int s = row & 1023;
  const float* src = kvfull + (size_t)row * 576;
  float v[8];
  float sq = 0.f;
#pragma unroll
  for (int i = 0; i < 8; i++) { v[i] = src[i * 64 + lane]; sq += v[i] * v[i]; }
  sq = wred_sum(sq);
  float rinv = rsqrtf(sq * (1.f / 512.f) + 1e-6f);
  float sq2 = 0.f;
#pragma unroll
  for (int i = 0; i < 8; i++) {
    v[i] = v[i] * rinv * wnorm[i * 64 + lane];
    sq2 += v[i] * v[i];
  }
  sq2 = wred_sum(sq2);
  u16* dst = kvnb + (size_t)row * 544;
#pragma unroll
  for (int i = 0; i < 8; i++) dst[1 + i * 64 + lane] = f2bf(v[i]);
  if (lane == 0) dst[0] = f2bf(sqrtf(sq2 + 1.0f));
  if (lane < 31) dst[513 + lane] = 0;
  if (lane < 32) {
    float x1 = src[512 + 2 * lane], x2 = src[512 + 2 * lane + 1];
    float c = fcos[s * 32 + lane], sn = fsin[s * 32 + lane];
    kpe[(size_t)row * 64 + 2 * lane]     = x1 * c - x2 * sn;
    kpe[(size_t)row * 64 + 2 * lane + 1] = x1 * sn + x2 * c;
  }
}

// ---------------------------------------------------------------------------
// KT/VT from kv2 (4096 x 4096 f32) + kpe.
// ---------------------------------------------------------------------------
__global__ __launch_bounds__(256)
void kt_vt_f32(const float* __restrict__ kv2, const float* __restrict__ kpe,
               float* __restrict__ KT, float* __restrict__ VT) {
  int r = blockIdx.x * 4 + (threadIdx.x >> 6);
  int lane = threadIdx.x & 63;
  int bh = r >> 10, s = r & 1023, b = bh >> 4, h = bh & 15;
  const float* src = kv2 + (size_t)(b * 1024 + s) * 4096 + h * 256;
  float e0 = src[2 * lane], e1 = src[2 * lane + 1];
  float sqk = e0 * e0 + e1 * e1;
  if (lane < 32) {
    float y1 = kpe[(size_t)(b * 1024 + s) * 64 + 2 * lane];
    float y2 = kpe[(size_t)(b * 1024 + s) * 64 + 2 * lane + 1];
    sqk += y1 * y1 + y2 * y2;
  }
  sqk = wred_sum(sqk);
  float v0 = src[128 + 2 * lane], v1 = src[128 + 2 * lane + 1];
  float sqv = wred_sum(v0 * v0 + v1 * v1);
  if (lane == 0) {
    KT[r] = sqrtf(sqk + 1.0f);
    VT[r] = sqrtf(sqv + 1.0f);
  }
}

// ---------------------------------------------------------------------------
// Naive fp32 attention + Lorentz normalize (R5, harness-verified).
// ---------------------------------------------------------------------------
__global__ __launch_bounds__(256)
void attn_f32(const float* __restrict__ qhat, const float* __restrict__ kv2,
              const float* __restrict__ kpe, const float* __restrict__ QT,
              const float* __restrict__ KT, const float* __restrict__ VT,
              u16* __restrict__ centb) {
  __shared__ float qr_[192];
  __shared__ float sc[1024];
  __shared__ float red[256];
  __shared__ float av[129];
  const int tid = threadIdx.x;
  const int bh = blockIdx.y, b = bh >> 4, h = bh & 15;
  const int s = blockIdx.x;
  const float twoSig = 2.0f / sqrtf(193.0f);

  if (tid < 192) qr_[tid] = qhat[((size_t)bh * 1024 + s) * 192 + tid];
  __syncthreads();
  const float qt = QT[bh * 1024 + s];

  float lmax = -1e30f;
  for (int t = tid; t <= s; t += 256) {
    const float* kb = kv2 + (size_t)(b * 1024 + t) * 4096 + h * 256;
    const float* pb = kpe + (size_t)(b * 1024 + t) * 64;
    float acc = 0.f;
    for (int i = 0; i < 128; i++) acc += qr_[i] * kb[i];
    for (int i = 0; i < 64; i++)  acc += qr_[128 + i] * pb[i];
    float v = 2.f + twoSig * (acc - qt * KT[bh * 1024 + t]);
    sc[t] = v;
    lmax = fmaxf(lmax, v);
  }
  red[tid] = lmax;
  __syncthreads();
  for (int o = 128; o > 0; o >>= 1) {
    if (tid < o) red[tid] = fmaxf(red[tid], red[tid + o]);
    __syncthreads();
  }
  const float m = red[0];
  __syncthreads();

  float lsum = 0.f;
  for (int t = tid; t <= s; t += 256) {
    float p = __expf(sc[t] - m);
    sc[t] = p;
    lsum += p;
  }
  red[tid] = lsum;
  __syncthreads();
  for (int o = 128; o > 0; o >>= 1) {
    if (tid < o) red[tid] += red[tid + o];
    __syncthreads();
  }
  const float Linv = 1.0f / red[0];
  __syncthreads();

  if (tid < 129) {
    float a = 0.f;
    if (tid == 0) {
      for (int t = 0; t <= s; t++) a += sc[t] * VT[bh * 1024 + t];
    } else {
      const float* vb = kv2 + (size_t)b * 1024 * 4096 + h * 256 + 128 + (tid - 1);
      for (int t = 0; t <= s; t++) a += sc[t] * vb[(size_t)t * 4096];
    }
    float an = a * Linv;
    av[tid] = an;
    red[tid] = (tid >= 1) ? an * an : 0.f;
  } else {
    red[tid] = 0.f;
  }
  __syncthreads();
  for (int o = 128; o > 0; o >>= 1) {
    if (tid < o) red[tid] += red[tid + o];
    __syncthreads();
  }
  const float a0 = av[0];
  const float neg = a0 * a0 - red[0];
  const float rr = rsqrtf(fmaxf(fabsf(neg), 1e-8f));
  if (tid < 129)
    centb[((size_t)b * 1024 + s) * 2080 + h * 129 + tid] = f2bf(av[tid] * rr);
}

// ---------------------------------------------------------------------------
// DIAGNOSTIC: Kb build (LINEAR): [bh][t][192] bf16 = [k_nope(128)|k_pe(64)].
// ---------------------------------------------------------------------------
__global__ __launch_bounds__(256)
void kb_build(const float* __restrict__ kv2, const float* __restrict__ kpe,
              u16* __restrict__ Kb) {
  int r = blockIdx.x * 4 + (threadIdx.x >> 6);   // bh*1024 + t
  int lane = threadIdx.x & 63;
  int bh = r >> 10, t = r & 1023, b = bh >> 4, h = bh & 15;
  const float* kn = kv2 + (size_t)(b * 1024 + t) * 4096 + h * 256;
  const float* pe = kpe + (size_t)(b * 1024 + t) * 64;
  u16* dst = Kb + (size_t)r * 192;
#pragma unroll
  for (int i = 0; i < 3; i++) {
    int k = i * 64 + lane;
    float v = (k < 128) ? kn[k] : pe[k - 128];
    dst[k] = f2bf(v);
  }
}

// ---------------------------------------------------------------------------
// DIAGNOSTIC: Vb build (LINEAR): transposed V, [bh][dv=144][t=1024] bf16.
// Row 0 = VT, rows 1..128 = v, rows 129..143 = 0. 4-pass transpose through a
// 64x33-float LDS tile (8448 B).
// ---------------------------------------------------------------------------
__global__ __launch_bounds__(256)
void vb_build(const float* __restrict__ kv2, const float* __restrict__ VT,
              u16* __restrict__ Vb) {
  __shared__ float ld[64][33];          // 8448 B
  int blk = blockIdx.x;                 // bh*16 + tile
  int bh = blk >> 4, t0 = (blk & 15) * 64;
  int b = bh >> 4, h = bh & 15;
  int tid = threadIdx.x;
  size_t base = (size_t)bh * 144 * 1024 + t0;
  if (tid < 64) Vb[base + tid] = f2bf(VT[(size_t)bh * 1024 + t0 + tid]);
  for (int i = tid; i < 15 * 64; i += 256)
    Vb[base + (size_t)(129 + (i >> 6)) * 1024 + (i & 63)] = 0;
  const int lrow = tid >> 5;            // 0..7
  const int lcol = tid & 31;            // 0..31
  const int wt = tid & 63;              // t within tile (write phase)
  const int wg = tid >> 6;              // 0..3
#pragma unroll
  for (int p = 0; p < 4; p++) {
    __syncthreads();
#pragma unroll
    for (int i = 0; i < 8; i++) {
      int row = i * 8 + lrow;
      ld[row][lcol] =
          kv2[(size_t)(b * 1024 + t0 + row) * 4096 + h * 256 + 128 + p * 32 + lcol];
    }
    __syncthreads();
#pragma unroll
    for (int c = 0; c < 8; c++) {
      int dvL = wg * 8 + c;             // 0..31
      Vb[base + (size_t)(1 + p * 32 + dvL) * 1024 + wt] = f2bf(ld[wt][dvL]);
    }
  }
}

// ---------------------------------------------------------------------------
// DIAGNOSTIC: fused MFMA flash attention (output not consumed this round).
// ---------------------------------------------------------------------------
__global__ __launch_bounds__(256)
void attn_mfma(const float* __restrict__ qhat, const float* __restrict__ QT,
               const float* __restrict__ KT,
               const u16* __restrict__ Kb, const u16* __restrict__ Vb,
               u16* __restrict__ centb) {
  __shared__ __align__(16) u16 Kt[64 * 200];     // 25600 B
  __shared__ __align__(16) u16 Vt[144 * 72];     // 20736 B
  __shared__ __align__(16) u16 Pl[4][16 * 72];   // 9216 B (per-wave P)

  const int tid = threadIdx.x;
  const int w = tid >> 6, lane = tid & 63;
  const int quad = lane >> 4, l16 = lane & 15;
  const int q0 = (15 - blockIdx.x) * 64;         // heavy q-tiles first
  const int bh = blockIdx.y, b = bh >> 4, h = bh & 15;
  const float twoSig = 2.0f / sqrtf(193.0f);

  bf16x8 qf[6];
  {
    const float* qrow =
        qhat + ((size_t)bh * 1024 + q0 + w * 16 + l16) * 192 + quad * 8;
#pragma unroll
    for (int c = 0; c < 6; c++) {
      f32x4 a = *(const f32x4*)(qrow + c * 32);
      f32x4 b2 = *(const f32x4*)(qrow + c * 32 + 4);
      qf[c] = cvt8(a, b2);
    }
  }
  float qtv[4];
#pragma unroll
  for (int j = 0; j < 4; j++)
    qtv[j] = QT[(size_t)bh * 1024 + q0 + w * 16 + quad * 4 + j];

  const int krow = tid >> 2, kc0 = tid & 3;

  float mrow[4], lrow[4];
  f32x4 acc_o[9];
#pragma unroll
  for (int j = 0; j < 4; j++) { mrow[j] = -1e30f; lrow[j] = 0.f; }
#pragma unroll
  for (int n = 0; n < 9; n++) acc_o[n] = (f32x4){0.f, 0.f, 0.f, 0.f};

  for (int t0 = 0; t0 <= q0; t0 += 64) {
    uint4 kreg[6];
    {
      const char* kbase = (const char*)Kb + ((size_t)bh * 1024 + t0 + krow) * 384;
#pragma unroll
      for (int i = 0; i < 6; i++)
        kreg[i] = *(const uint4*)(kbase + (kc0 + 4 * i) * 16);
    }
    uint4 vreg[5];
#pragma unroll
    for (int i = 0; i < 5; i++) {
      int c = tid + i * 256;
      if (c < 1152)
        vreg[i] = *(const uint4*)((const char*)Vb +
                    ((size_t)bh * 144 + (c >> 3)) * 2048 + t0 * 2 + (c & 7) * 16);
    }
    __syncthreads();
#pragma unroll
    for (int i = 0; i < 6; i++)
      *(uint4*)&Kt[krow * 200 + (kc0 + 4 * i) * 8] = kreg[i];
#pragma unroll
    for (int i = 0; i < 5; i++) {
      int c = tid + i * 256;
      if (c < 1152) *(uint4*)&Vt[(c >> 3) * 72 + (c & 7) * 8] = vreg[i];
    }
    __syncthreads();

    f32x4 sc[4];
#pragma unroll
    for (int f = 0; f < 4; f++) sc[f] = (f32x4){0.f, 0.f, 0.f, 0.f};
#pragma unroll
    for (int c = 0; c < 6; c++) {
#pragma unroll
      for (int f = 0; f < 4; f++) {
        bf16x8 kf = *(const bf16x8*)&Kt[(f * 16 + l16) * 200 + c * 32 + quad * 8];
        sc[f] = __builtin_amdgcn_mfma_f32_16x16x32_bf16(qf[c], kf, sc[f], 0, 0, 0);
      }
    }

    float vsc[4][4];
#pragma unroll
    for (int f = 0; f < 4; f++) {
      float ktf = KT[(size_t)bh * 1024 + t0 + f * 16 + l16];
#pragma unroll
      for (int j = 0; j < 4; j++)
        vsc[f][j] = 2.f + twoSig * (sc[f][j] - qtv[j] * ktf);
    }
    if (t0 == q0) {
#pragma unroll
      for (int f = 0; f < 4; f++) {
        int tg = f * 16 + l16;
#pragma unroll
        for (int j = 0; j < 4; j++)
          if (tg > w * 16 + quad * 4 + j) vsc[f][j] = -1e30f;
      }
    }

#pragma unroll
    for (int j = 0; j < 4; j++) {
      float mx = fmaxf(fmaxf(vsc[0][j], vsc[1][j]), fmaxf(vsc[2][j], vsc[3][j]));
      mx = fmaxf(mx, __shfl_xor(mx, 1));
      mx = fmaxf(mx, __shfl_xor(mx, 2));
      mx = fmaxf(mx, __shfl_xor(mx, 4));
      mx = fmaxf(mx, __shfl_xor(mx, 8));
      float mnew = fmaxf(mrow[j], mx);
      float scl = __expf(mrow[j] - mnew);
      mrow[j] = mnew;
      float rs = 0.f;
#pragma unroll
      for (int f = 0; f < 4; f++) {
        float p = __expf(vsc[f][j] - mnew);
        rs += p;
        Pl[w][(quad * 4 + j) * 72 + f * 16 + l16] = f2bf(p);
      }
      rs += __shfl_xor(rs, 1);
      rs += __shfl_xor(rs, 2);
      rs += __shfl_xor(rs, 4);
      rs += __shfl_xor(rs, 8);
      lrow[j] = lrow[j] * scl + rs;
#pragma unroll
      for (int n = 0; n < 9; n++) acc_o[n][j] *= scl;
    }

    bf16x8 pa[2];
#pragma unroll
    for (int kc = 0; kc < 2; kc++)
      pa[kc] = *(const bf16x8*)&Pl[w][l16 * 72 + kc * 32 + quad * 8];
#pragma unroll
    for (int n = 0; n < 9; n++) {
#pragma unroll
      for (int kc = 0; kc < 2; kc++) {
        bf16x8 vf = *(const bf16x8*)&Vt[(n * 16 + l16) * 72 + kc * 32 + quad * 8];
        acc_o[n] = __builtin_amdgcn_mfma_f32_16x16x32_bf16(pa[kc], vf, acc_o[n],
                                                           0, 0, 0);
      }
    }
  }

  float linv[4], rrj[4];
#pragma unroll
  for (int j = 0; j < 4; j++) linv[j] = 1.0f / lrow[j];
#pragma unroll
  for (int j = 0; j < 4; j++) {
    float tot = 0.f;
#pragma unroll
    for (int n = 0; n < 9; n++) {
      float an = acc_o[n][j] * linv[j];
      tot += an * an;
    }
    tot += __shfl_xor(tot, 1);
    tot += __shfl_xor(tot, 2);
    tot += __shfl_xor(tot, 4);
    tot += __shfl_xor(tot, 8);
    float a0 = (l16 == 0) ? acc_o[0][j] * linv[j] : 0.f;
    a0 += __shfl_xor(a0, 1);
    a0 += __shfl_xor(a0, 2);
    a0 += __shfl_xor(a0, 4);
    a0 += __shfl_xor(a0, 8);
    float neg = 2.f * a0 * a0 - tot;
    rrj[j] = rsqrtf(fmaxf(fabsf(neg), 1e-8f));
  }
  size_t rowb = ((size_t)b * 1024 + q0 + w * 16 + quad * 4) * 2080 + h * 129;
#pragma unroll
  for (int n = 0; n < 9; n++) {
    int dv = n * 16 + l16;
    if (dv <= 128) {
#pragma unroll
      for (int j = 0; j < 4; j++)
        centb[rowb + (size_t)j * 2080 + dv] = f2bf(acc_o[n][j] * linv[j] * rrj[j]);
    }
  }
  if (h == 15) {
    for (int idx = tid; idx < 64 * 16; idx += 256) {
      int r = idx >> 4, c = idx & 15;
      centb[((size_t)b * 1024 + q0 + r) * 2080 + 2064 + c] = 0;
    }
  }
}

// ---------------------------------------------------------------------------
__global__ __launch_bounds__(256)
void out_time(float* __restrict__ out) {
  int row = blockIdx.x * 4 + (threadIdx.x >> 6);
  int lane = threadIdx.x & 63;
  float* p = out + (size_t)row * 2048;
  float sq = 0.f;
#pragma unroll
  for (int i = 0; i < 32; i++) {
    int c = 1 + i * 64 + lane;
    if (c < 2048) { float v = p[c]; sq += v * v; }
  }
  sq = wred_sum(sq);
  if (lane == 0) p[0] = sqrtf(sq + 1.0f);
}

// ---------------------------------------------------------------------------
extern "C" void kernel_launch(void* const* d_in, const int* in_sizes, int n_in,
                              void* d_out, int out_size, void* d_ws, size_t ws_size,
                              hipStream_t stream) {
  const float* x      = (const float*)d_in[0];
  const float* fcos   = (const float*)d_in[1];
  const float* fsin   = (const float*)d_in[2];
  // d_in[3] = mask (causal, analytic)
  const float* wq_w   = (const float*)d_in[4];
  const float* wq_b   = (const float*)d_in[5];
  const float* wkva_w = (const float*)d_in[6];
  const float* wkva_b = (const float*)d_in[7];
  const float* kvnw   = (const float*)d_in[8];
  const float* wkvb_w = (const float*)d_in[9];
  const float* wkvb_b = (const float*)d_in[10];
  const float* wo_w   = (const float*)d_in[11];
  const float* wo_b   = (const float*)d_in[12];

  // ---- workspace (~169.9 MB), R5 layout exactly ----
  char* ws = (char*)d_ws;
  float* qhat   = (float*)(ws);                            // 50,331,648
  float* QT     = (float*)(ws + 50331648);                 // 262,144
  float* KT     = (float*)(ws + 50593792);                 // 262,144
  float* VT     = (float*)(ws + 50855936);                 // 262,144
  float* kpe    = (float*)(ws + 51118080);                 // 1,048,576
  const size_t offA = 52166656;   // qpre f32 (50.3M) -> kv2 f32 (67.1M)
  float* qpre   = (float*)(ws + offA);
  float* kv2    = (float*)(ws + offA);
  const size_t offB = offA + 67108864;  // xb bf16 (16.8M) -> centb bf16 (17.0M)
  u16*   xb     = (u16*)  (ws + offB);
  u16*   centb  = (u16*)  (ws + offB);
  const size_t offC = offB + 17039360;  // W0b (12.6M) -> W3b (8.5M)
  u16*   W0b    = (u16*)  (ws + offC);
  u16*   W3b    = (u16*)  (ws + offC);
  const size_t offD = offC + 12582912;  // small weights + kvfull
  u16*   W1b    = (u16*)  (ws + offD);                     // 2,621,440
  u16*   W2b    = (u16*)  (ws + offD + 2621440);           // 4,456,448
  u16*   kvnb   = (u16*)  (ws + offD + 7077888);           // 4,456,448
  float* kvfull = (float*)(ws + offD + 11534336);          // 9,437,184

  // Diagnostic buffers: all inside the dead region [offC, offC+33.5MB).
  // Outputs never consumed; overwritten by W3b pad_convert afterwards.
  u16* Kb_diag   = (u16*)(ws + offC);   // needs 25.2MB <= 33.5MB
  u16* Vb_diag   = (u16*)(ws + offC);   // overlaps Kb_diag (content irrelevant)
  u16* cent_diag = (u16*)(ws + offC);   // overlaps too (content irrelevant)

  int t;
  // 1. convert x / wq
  t = 4096 * 2048;
  pad_convert<<<(t + 255) / 256, 256, 0, stream>>>(x, xb, 4096, 2048, 2048, t);
  t = 3072 * 2048;
  pad_convert<<<(t + 255) / 256, 256, 0, stream>>>(wq_w, W0b, 3072, 2048, 2048, t);
  // 2. qpre = x @ wq^T (fp32 out)
  gemm_bt<<<dim3(24, 32), 256, 0, stream>>>(xb, W0b, wq_b, qpre, 2048, 3072, 3072);
  // 3. q assembly
  q_assemble_f32<<<16384, 256, 0, stream>>>(qpre, fcos, fsin, qhat, QT);
  // 4. kvfull = x @ wkva^T (fp32 out)
  t = 640 * 2048;
  pad_convert<<<(t + 255) / 256, 256, 0, stream>>>(wkva_w, W1b, 576, 2048, 2048, t);
  gemm_bt<<<dim3(5, 32), 256, 0, stream>>>(xb, W1b, wkva_b, kvfull, 2048, 576, 576);
  // 5. RMSNorm + project + rope(k_pe); kvn stored bf16
  kv_assemble1_f32<<<1024, 256, 0, stream>>>(kvfull, kvnw, fcos, fsin, kvnb, kpe);
  // 6. kv2 = kvn @ wkvb^T (fp32 out; overwrites qpre region — qpre dead)
  t = 4096 * 544;
  pad_convert<<<(t + 255) / 256, 256, 0, stream>>>(wkvb_w, W2b, 4096, 513, 544, t);
  gemm_bt<<<dim3(32, 32), 256, 0, stream>>>(kvnb, W2b, wkvb_b, kv2, 544, 4096, 4096);
  // 7. KT / VT
  kt_vt_f32<<<16384, 256, 0, stream>>>(kv2, kpe, KT, VT);
  // 8. attention (R5 path, consumed) -> centb bf16 at offB
  attn_f32<<<dim3(1024, 64), 256, 0, stream>>>(qhat, kv2, kpe, QT, KT, VT, centb);
  // 8b. DIAGNOSTIC launches (outputs dead; region overwritten by W3b below)
  kb_build<<<16384, 256, 0, stream>>>(kv2, kpe, Kb_diag);
  vb_build<<<1024, 256, 0, stream>>>(kv2, VT, Vb_diag);
  attn_mfma<<<dim3(16, 64), 256, 0, stream>>>(qhat, QT, KT, Kb_diag, Vb_diag,
                                              cent_diag);
  // 9. y = cent @ wo^T -> d_out cols 1..2047 (fp32)
  t = 2048 * 2080;
  pad_convert<<<(t + 255) / 256, 256, 0, stream>>>(wo_w, W3b, 2047, 2064, 2080, t);
  gemm_bt<<<dim3(16, 32), 256, 0, stream>>>(centb, W3b, wo_b, (float*)d_out + 1,
                                            2080, 2048, 2047);
  // 10. time component
  out_time<<<1024, 256, 0, stream>>>((float*)d_out);
}

// Round 5
// 8435.694 us; speedup vs baseline: 1.0152x; 1.0152x over previous
//
#include <hip/hip_runtime.h>
#include <cstdint>

// ---------------------------------------------------------------------------
// LorentzMLA on MI355X (gfx950). R10: SELF-VERIFYING dual-path round.
// Consumed pipeline = R5 verbatim (passes). MFMA attention path runs as a
// diagnostic on b=0 with NON-overlapping buffers (R9 had them aliased, so
// numerics were never tested). An on-device comparator diffs cent_diag vs
// attn_f32's centb and encodes the verdict as spin-kernel durations visible
// in the rocprof dispatch table:
//   vfy_spinA ~12ms: >2000 entries |diff|>0.25        (structural error)
//   vfy_spinB ~16ms: >100 time-col entries bad        (VT/a0 path error)
//   vfy_spinC ~20ms: >50% entries bad                 (global layout error)
// No spins in top-5 => MFMA path numerically verified => next round ships it.
// ---------------------------------------------------------------------------

typedef unsigned short u16;
typedef __bf16 bf16x8 __attribute__((ext_vector_type(8)));
typedef float f32x4 __attribute__((ext_vector_type(4)));

#define DEV __device__ __forceinline__

DEV u16 f2bf(float f) {
  unsigned u = __builtin_bit_cast(unsigned, f);
  u = u + 0x7fffu + ((u >> 16) & 1u);
  return (u16)(u >> 16);
}

DEV void async16(void* lds, const void* g) {
  __builtin_amdgcn_global_load_lds(
      (__attribute__((address_space(1))) void*)(uintptr_t)g,
      (__attribute__((address_space(3))) void*)lds, 16, 0, 0);
}

DEV float wred_sum(float v) {
  v += __shfl_xor(v, 1);  v += __shfl_xor(v, 2);  v += __shfl_xor(v, 4);
  v += __shfl_xor(v, 8);  v += __shfl_xor(v, 16); v += __shfl_xor(v, 32);
  return v;
}

DEV bf16x8 cvt8(f32x4 a, f32x4 b) {
  union { bf16x8 v; u16 u[8]; } r;
#pragma unroll
  for (int i = 0; i < 4; i++) { r.u[i] = f2bf(a[i]); r.u[4 + i] = f2bf(b[i]); }
  return r.v;
}

// ---------------------------------------------------------------------------
// fp32 -> bf16 with zero padding. dst (rd x cd), src (rs x cs).
// ---------------------------------------------------------------------------
__global__ __launch_bounds__(256)
void pad_convert(const float* __restrict__ src, u16* __restrict__ dst,
                 int rs, int cs, int cd, int total) {
  int idx = blockIdx.x * 256 + threadIdx.x;
  if (idx >= total) return;
  int r = idx / cd, c = idx - r * cd;
  float v = (r < rs && c < cs) ? src[(size_t)r * cs + c] : 0.f;
  dst[idx] = f2bf(v);
}

// ---------------------------------------------------------------------------
// out[m][n] = sum_k A[m][k]*W[n][k] + bias[n].  A: MxK bf16, W: NxK bf16.
// ---------------------------------------------------------------------------
__global__ __launch_bounds__(256)
void gemm_bt(const u16* __restrict__ A, const u16* __restrict__ W,
             const float* __restrict__ bias, float* __restrict__ outF,
             int K, int ldo, int nstore) {
  __shared__ __align__(16) u16 As[128 * 32];
  __shared__ __align__(16) u16 Bs[128 * 32];
  const int tid = threadIdx.x;
  const int w = tid >> 6, lane = tid & 63;
  const int quad = lane >> 4, l16 = lane & 15;
  const int bm = blockIdx.y * 128, bn = blockIdx.x * 128;
  const int wm = (w & 1) * 64, wn = (w >> 1) * 64;
  const int sr = lane >> 2;
  const int sc = (lane & 3) * 8;

  f32x4 acc[4][4];
#pragma unroll
  for (int i = 0; i < 4; i++)
#pragma unroll
    for (int j = 0; j < 4; j++) acc[i][j] = (f32x4){0.f, 0.f, 0.f, 0.f};

  const u16* Ab = A + (size_t)bm * K;
  const u16* Wb = W + (size_t)bn * K;

  for (int k0 = 0; k0 < K; k0 += 32) {
    __syncthreads();
#pragma unroll
    for (int i = 0; i < 2; ++i) {
      int rr = w * 32 + i * 16;
      async16((char*)&As[rr * 32] + (size_t)lane * 16,
              Ab + (size_t)(rr + sr) * K + k0 + sc);
      async16((char*)&Bs[rr * 32] + (size_t)lane * 16,
              Wb + (size_t)(rr + sr) * K + k0 + sc);
    }
    __syncthreads();
    bf16x8 aF[4], bF[4];
#pragma unroll
    for (int i = 0; i < 4; i++)
      aF[i] = *(const bf16x8*)&As[(wm + i * 16 + l16) * 32 + quad * 8];
#pragma unroll
    for (int i = 0; i < 4; i++)
      bF[i] = *(const bf16x8*)&Bs[(wn + i * 16 + l16) * 32 + quad * 8];
#pragma unroll
    for (int im = 0; im < 4; im++)
#pragma unroll
      for (int in = 0; in < 4; in++)
        acc[im][in] = __builtin_amdgcn_mfma_f32_16x16x32_bf16(
            aF[im], bF[in], acc[im][in], 0, 0, 0);
  }

#pragma unroll
  for (int im = 0; im < 4; im++) {
#pragma unroll
    for (int in = 0; in < 4; in++) {
      int gn = bn + wn + in * 16 + l16;
      if (gn >= nstore) continue;
      float bv = bias[gn];
#pragma unroll
      for (int j = 0; j < 4; j++) {
        int gm = bm + wm + im * 16 + quad * 4 + j;
        outF[(size_t)gm * ldo + gn] = acc[im][in][j] + bv;
      }
    }
  }
}

// ---------------------------------------------------------------------------
__global__ __launch_bounds__(256)
void q_assemble_f32(const float* __restrict__ qpre, const float* __restrict__ fcos,
                    const float* __restrict__ fsin, float* __restrict__ qhat,
                    float* __restrict__ QT) {
  int row = blockIdx.x * 4 + (threadIdx.x >> 6);   // = bh*1024 + s
  int lane = threadIdx.x & 63;
  int b = row >> 14, h = (row >> 10) & 15, s = row & 1023;
  const float* src = qpre + (size_t)(b * 1024 + s) * 3072 + h * 192;
  float e0 = src[2 * lane], e1 = src[2 * lane + 1];
  float y1 = 0.f, y2 = 0.f;
  float sq = e0 * e0 + e1 * e1;
  if (lane < 32) {
    float x1 = src[128 + 2 * lane], x2 = src[128 + 2 * lane + 1];
    float c = fcos[s * 32 + lane], sn = fsin[s * 32 + lane];
    y1 = x1 * c - x2 * sn;
    y2 = x1 * sn + x2 * c;
    sq += x1 * x1 + x2 * x2;
  }
  sq = wred_sum(sq);
  float* dst = qhat + (size_t)row * 192;
  dst[2 * lane] = e0;
  dst[2 * lane + 1] = e1;
  if (lane < 32) { dst[128 + 2 * lane] = y1; dst[128 + 2 * lane + 1] = y2; }
  if (lane == 0) QT[row] = sqrtf(sq + 1.0f);
}

// ---------------------------------------------------------------------------
__global__ __launch_bounds__(256)
void kv_assemble1_f32(const float* __restrict__ kvfull, const float* __restrict__ wnorm,
                      const float* __restrict__ fcos, const float* __restrict__ fsin,
                      u16* __restrict__ kvnb, float* __restrict__ kpe) {
  int row = blockIdx.x * 4 + (threadIdx.x >> 6);   // b*1024 + s
  int lane = threadIdx.x & 63;
  int s = row & 1023;
  const float* src = kvfull + (size_t)row * 576;
  float v[8];
  float sq = 0.f;
#pragma unroll
  for (int i = 0; i < 8; i++) { v[i] = src[i * 64 + lane]; sq += v[i] * v[i]; }
  sq = wred_sum(sq);
  float rinv = rsqrtf(sq * (1.f / 512.f) + 1e-6f);
  float sq2 = 0.f;
#pragma unroll
  for (int i = 0; i < 8; i++) {
    v[i] = v[i] * rinv * wnorm[i * 64 + lane];
    sq2 += v[i] * v[i];
  }
  sq2 = wred_sum(sq2);
  u16* dst = kvnb + (size_t)row * 544;
#pragma unroll
  for (int i = 0; i < 8; i++) dst[1 + i * 64 + lane] = f2bf(v[i]);
  if (lane == 0) dst[0] = f2bf(sqrtf(sq2 + 1.0f));
  if (lane < 31) dst[513 + lane] = 0;
  if (lane < 32) {
    float x1 = src[512 + 2 * lane], x2 = src[512 + 2 * lane + 1];
    float c = fcos[s * 32 + lane], sn = fsin[s * 32 + lane];
    kpe[(size_t)row * 64 + 2 * lane]     = x1 * c - x2 * sn;
    kpe[(size_t)row * 64 + 2 * lane + 1] = x1 * sn + x2 * c;
  }
}

// ---------------------------------------------------------------------------
__global__ __launch_bounds__(256)
void kt_vt_f32(const float* __restrict__ kv2, const float* __restrict__ kpe,
               float* __restrict__ KT, float* __restrict__ VT) {
  int r = blockIdx.x * 4 + (threadIdx.x >> 6);
  int lane = threadIdx.x & 63;
  int bh = r >> 10, s = r & 1023, b = bh >> 4, h = bh & 15;
  const float* src = kv2 + (size_t)(b * 1024 + s) * 4096 + h * 256;
  float e0 = src[2 * lane], e1 = src[2 * lane + 1];
  float sqk = e0 * e0 + e1 * e1;
  if (lane < 32) {
    float y1 = kpe[(size_t)(b * 1024 + s) * 64 + 2 * lane];
    float y2 = kpe[(size_t)(b * 1024 + s) * 64 + 2 * lane + 1];
    sqk += y1 * y1 + y2 * y2;
  }
  sqk = wred_sum(sqk);
  float v0 = src[128 + 2 * lane], v1 = src[128 + 2 * lane + 1];
  float sqv = wred_sum(v0 * v0 + v1 * v1);
  if (lane == 0) {
    KT[r] = sqrtf(sqk + 1.0f);
    VT[r] = sqrtf(sqv + 1.0f);
  }
}

// ---------------------------------------------------------------------------
// Naive fp32 attention + Lorentz normalize (R5, harness-verified).
// ---------------------------------------------------------------------------
__global__ __launch_bounds__(256)
void attn_f32(const float* __restrict__ qhat, const float* __restrict__ kv2,
              const float* __restrict__ kpe, const float* __restrict__ QT,
              const float* __restrict__ KT, const float* __restrict__ VT,
              u16* __restrict__ centb) {
  __shared__ float qr_[192];
  __shared__ float sc[1024];
  __shared__ float red[256];
  __shared__ float av[129];
  const int tid = threadIdx.x;
  const int bh = blockIdx.y, b = bh >> 4, h = bh & 15;
  const int s = blockIdx.x;
  const float twoSig = 2.0f / sqrtf(193.0f);

  if (tid < 192) qr_[tid] = qhat[((size_t)bh * 1024 + s) * 192 + tid];
  __syncthreads();
  const float qt = QT[bh * 1024 + s];

  float lmax = -1e30f;
  for (int t = tid; t <= s; t += 256) {
    const float* kb = kv2 + (size_t)(b * 1024 + t) * 4096 + h * 256;
    const float* pb = kpe + (size_t)(b * 1024 + t) * 64;
    float acc = 0.f;
    for (int i = 0; i < 128; i++) acc += qr_[i] * kb[i];
    for (int i = 0; i < 64; i++)  acc += qr_[128 + i] * pb[i];
    float v = 2.f + twoSig * (acc - qt * KT[bh * 1024 + t]);
    sc[t] = v;
    lmax = fmaxf(lmax, v);
  }
  red[tid] = lmax;
  __syncthreads();
  for (int o = 128; o > 0; o >>= 1) {
    if (tid < o) red[tid] = fmaxf(red[tid], red[tid + o]);
    __syncthreads();
  }
  const float m = red[0];
  __syncthreads();

  float lsum = 0.f;
  for (int t = tid; t <= s; t += 256) {
    float p = __expf(sc[t] - m);
    sc[t] = p;
    lsum += p;
  }
  red[tid] = lsum;
  __syncthreads();
  for (int o = 128; o > 0; o >>= 1) {
    if (tid < o) red[tid] += red[tid + o];
    __syncthreads();
  }
  const float Linv = 1.0f / red[0];
  __syncthreads();

  if (tid < 129) {
    float a = 0.f;
    if (tid == 0) {
      for (int t = 0; t <= s; t++) a += sc[t] * VT[bh * 1024 + t];
    } else {
      const float* vb = kv2 + (size_t)b * 1024 * 4096 + h * 256 + 128 + (tid - 1);
      for (int t = 0; t <= s; t++) a += sc[t] * vb[(size_t)t * 4096];
    }
    float an = a * Linv;
    av[tid] = an;
    red[tid] = (tid >= 1) ? an * an : 0.f;
  } else {
    red[tid] = 0.f;
  }
  __syncthreads();
  for (int o = 128; o > 0; o >>= 1) {
    if (tid < o) red[tid] += red[tid + o];
    __syncthreads();
  }
  const float a0 = av[0];
  const float neg = a0 * a0 - red[0];
  const float rr = rsqrtf(fmaxf(fabsf(neg), 1e-8f));
  if (tid < 129)
    centb[((size_t)b * 1024 + s) * 2080 + h * 129 + tid] = f2bf(av[tid] * rr);
}

// ---------------------------------------------------------------------------
// Kb build (LINEAR): [bh][t][192] bf16 = [k_nope(128)|k_pe(64)].
// ---------------------------------------------------------------------------
__global__ __launch_bounds__(256)
void kb_build(const float* __restrict__ kv2, const float* __restrict__ kpe,
              u16* __restrict__ Kb) {
  int r = blockIdx.x * 4 + (threadIdx.x >> 6);   // bh*1024 + t
  int lane = threadIdx.x & 63;
  int bh = r >> 10, t = r & 1023, b = bh >> 4, h = bh & 15;
  const float* kn = kv2 + (size_t)(b * 1024 + t) * 4096 + h * 256;
  const float* pe = kpe + (size_t)(b * 1024 + t) * 64;
  u16* dst = Kb + (size_t)r * 192;
#pragma unroll
  for (int i = 0; i < 3; i++) {
    int k = i * 64 + lane;
    float v = (k < 128) ? kn[k] : pe[k - 128];
    dst[k] = f2bf(v);
  }
}

// ---------------------------------------------------------------------------
// Vb build (LINEAR): transposed V, [bh][dv=144][t=1024] bf16. Row 0 = VT,
// rows 1..128 = v, rows 129..143 = 0. 4-pass 64x33-float LDS tile (8448 B).
// ---------------------------------------------------------------------------
__global__ __launch_bounds__(256)
void vb_build(const float* __restrict__ kv2, const float* __restrict__ VT,
              u16* __restrict__ Vb) {
  __shared__ float ld[64][33];
  int blk = blockIdx.x;                 // bh*16 + tile
  int bh = blk >> 4, t0 = (blk & 15) * 64;
  int b = bh >> 4, h = bh & 15;
  int tid = threadIdx.x;
  size_t base = (size_t)bh * 144 * 1024 + t0;
  if (tid < 64) Vb[base + tid] = f2bf(VT[(size_t)bh * 1024 + t0 + tid]);
  for (int i = tid; i < 15 * 64; i += 256)
    Vb[base + (size_t)(129 + (i >> 6)) * 1024 + (i & 63)] = 0;
  const int lrow = tid >> 5;            // 0..7
  const int lcol = tid & 31;            // 0..31
  const int wt = tid & 63;              // t within tile (write phase)
  const int wg = tid >> 6;              // 0..3
#pragma unroll
  for (int p = 0; p < 4; p++) {
    __syncthreads();
#pragma unroll
    for (int i = 0; i < 8; i++) {
      int row = i * 8 + lrow;
      ld[row][lcol] =
          kv2[(size_t)(b * 1024 + t0 + row) * 4096 + h * 256 + 128 + p * 32 + lcol];
    }
    __syncthreads();
#pragma unroll
    for (int c = 0; c < 8; c++) {
      int dvL = wg * 8 + c;             // 0..31
      Vb[base + (size_t)(1 + p * 32 + dvL) * 1024 + wt] = f2bf(ld[wt][dvL]);
    }
  }
}

// ---------------------------------------------------------------------------
// Fused MFMA flash attention (diagnostic this round).
// ---------------------------------------------------------------------------
__global__ __launch_bounds__(256)
void attn_mfma(const float* __restrict__ qhat, const float* __restrict__ QT,
               const float* __restrict__ KT,
               const u16* __restrict__ Kb, const u16* __restrict__ Vb,
               u16* __restrict__ centb) {
  __shared__ __align__(16) u16 Kt[64 * 200];
  __shared__ __align__(16) u16 Vt[144 * 72];
  __shared__ __align__(16) u16 Pl[4][16 * 72];

  const int tid = threadIdx.x;
  const int w = tid >> 6, lane = tid & 63;
  const int quad = lane >> 4, l16 = lane & 15;
  const int q0 = (15 - blockIdx.x) * 64;
  const int bh = blockIdx.y, b = bh >> 4, h = bh & 15;
  const float twoSig = 2.0f / sqrtf(193.0f);

  bf16x8 qf[6];
  {
    const float* qrow =
        qhat + ((size_t)bh * 1024 + q0 + w * 16 + l16) * 192 + quad * 8;
#pragma unroll
    for (int c = 0; c < 6; c++) {
      f32x4 a = *(const f32x4*)(qrow + c * 32);
      f32x4 b2 = *(const f32x4*)(qrow + c * 32 + 4);
      qf[c] = cvt8(a, b2);
    }
  }
  float qtv[4];
#pragma unroll
  for (int j = 0; j < 4; j++)
    qtv[j] = QT[(size_t)bh * 1024 + q0 + w * 16 + quad * 4 + j];

  const int krow = tid >> 2, kc0 = tid & 3;

  float mrow[4], lrow[4];
  f32x4 acc_o[9];
#pragma unroll
  for (int j = 0; j < 4; j++) { mrow[j] = -1e30f; lrow[j] = 0.f; }
#pragma unroll
  for (int n = 0; n < 9; n++) acc_o[n] = (f32x4){0.f, 0.f, 0.f, 0.f};

  for (int t0 = 0; t0 <= q0; t0 += 64) {
    uint4 kreg[6];
    {
      const char* kbase = (const char*)Kb + ((size_t)bh * 1024 + t0 + krow) * 384;
#pragma unroll
      for (int i = 0; i < 6; i++)
        kreg[i] = *(const uint4*)(kbase + (kc0 + 4 * i) * 16);
    }
    uint4 vreg[5];
#pragma unroll
    for (int i = 0; i < 5; i++) {
      int c = tid + i * 256;
      if (c < 1152)
        vreg[i] = *(const uint4*)((const char*)Vb +
                    ((size_t)bh * 144 + (c >> 3)) * 2048 + t0 * 2 + (c & 7) * 16);
    }
    __syncthreads();
#pragma unroll
    for (int i = 0; i < 6; i++)
      *(uint4*)&Kt[krow * 200 + (kc0 + 4 * i) * 8] = kreg[i];
#pragma unroll
    for (int i = 0; i < 5; i++) {
      int c = tid + i * 256;
      if (c < 1152) *(uint4*)&Vt[(c >> 3) * 72 + (c & 7) * 8] = vreg[i];
    }
    __syncthreads();

    f32x4 sc[4];
#pragma unroll
    for (int f = 0; f < 4; f++) sc[f] = (f32x4){0.f, 0.f, 0.f, 0.f};
#pragma unroll
    for (int c = 0; c < 6; c++) {
#pragma unroll
      for (int f = 0; f < 4; f++) {
        bf16x8 kf = *(const bf16x8*)&Kt[(f * 16 + l16) * 200 + c * 32 + quad * 8];
        sc[f] = __builtin_amdgcn_mfma_f32_16x16x32_bf16(qf[c], kf, sc[f], 0, 0, 0);
      }
    }

    float vsc[4][4];
#pragma unroll
    for (int f = 0; f < 4; f++) {
      float ktf = KT[(size_t)bh * 1024 + t0 + f * 16 + l16];
#pragma unroll
      for (int j = 0; j < 4; j++)
        vsc[f][j] = 2.f + twoSig * (sc[f][j] - qtv[j] * ktf);
    }
    if (t0 == q0) {
#pragma unroll
      for (int f = 0; f < 4; f++) {
        int tg = f * 16 + l16;
#pragma unroll
        for (int j = 0; j < 4; j++)
          if (tg > w * 16 + quad * 4 + j) vsc[f][j] = -1e30f;
      }
    }

#pragma unroll
    for (int j = 0; j < 4; j++) {
      float mx = fmaxf(fmaxf(vsc[0][j], vsc[1][j]), fmaxf(vsc[2][j], vsc[3][j]));
      mx = fmaxf(mx, __shfl_xor(mx, 1));
      mx = fmaxf(mx, __shfl_xor(mx, 2));
      mx = fmaxf(mx, __shfl_xor(mx, 4));
      mx = fmaxf(mx, __shfl_xor(mx, 8));
      float mnew = fmaxf(mrow[j], mx);
      float scl = __expf(mrow[j] - mnew);
      mrow[j] = mnew;
      float rs = 0.f;
#pragma unroll
      for (int f = 0; f < 4; f++) {
        float p = __expf(vsc[f][j] - mnew);
        rs += p;
        Pl[w][(quad * 4 + j) * 72 + f * 16 + l16] = f2bf(p);
      }
      rs += __shfl_xor(rs, 1);
      rs += __shfl_xor(rs, 2);
      rs += __shfl_xor(rs, 4);
      rs += __shfl_xor(rs, 8);
      lrow[j] = lrow[j] * scl + rs;
#pragma unroll
      for (int n = 0; n < 9; n++) acc_o[n][j] *= scl;
    }

    bf16x8 pa[2];
#pragma unroll
    for (int kc = 0; kc < 2; kc++)
      pa[kc] = *(const bf16x8*)&Pl[w][l16 * 72 + kc * 32 + quad * 8];
#pragma unroll
    for (int n = 0; n < 9; n++) {
#pragma unroll
      for (int kc = 0; kc < 2; kc++) {
        bf16x8 vf = *(const bf16x8*)&Vt[(n * 16 + l16) * 72 + kc * 32 + quad * 8];
        acc_o[n] = __builtin_amdgcn_mfma_f32_16x16x32_bf16(pa[kc], vf, acc_o[n],
                                                           0, 0, 0);
      }
    }
  }

  float linv[4], rrj[4];
#pragma unroll
  for (int j = 0; j < 4; j++) linv[j] = 1.0f / lrow[j];
#pragma unroll
  for (int j = 0; j < 4; j++) {
    float tot = 0.f;
#pragma unroll
    for (int n = 0; n < 9; n++) {
      float an = acc_o[n][j] * linv[j];
      tot += an * an;
    }
    tot += __shfl_xor(tot, 1);
    tot += __shfl_xor(tot, 2);
    tot += __shfl_xor(tot, 4);
    tot += __shfl_xor(tot, 8);
    float a0 = (l16 == 0) ? acc_o[0][j] * linv[j] : 0.f;
    a0 += __shfl_xor(a0, 1);
    a0 += __shfl_xor(a0, 2);
    a0 += __shfl_xor(a0, 4);
    a0 += __shfl_xor(a0, 8);
    float neg = 2.f * a0 * a0 - tot;
    rrj[j] = rsqrtf(fmaxf(fabsf(neg), 1e-8f));
  }
  size_t rowb = ((size_t)b * 1024 + q0 + w * 16 + quad * 4) * 2080 + h * 129;
#pragma unroll
  for (int n = 0; n < 9; n++) {
    int dv = n * 16 + l16;
    if (dv <= 128) {
#pragma unroll
      for (int j = 0; j < 4; j++)
        centb[rowb + (size_t)j * 2080 + dv] = f2bf(acc_o[n][j] * linv[j] * rrj[j]);
    }
  }
  if (h == 15) {
    for (int idx = tid; idx < 64 * 16; idx += 256) {
      int r = idx >> 4, c = idx & 15;
      centb[((size_t)b * 1024 + q0 + r) * 2080 + 2064 + c] = 0;
    }
  }
}

// ---------------------------------------------------------------------------
// Verdict machinery: compare cent_diag (MFMA, b=0) vs centb (attn_f32, b=0)
// and encode the result as spin durations visible in rocprof.
// ---------------------------------------------------------------------------
__global__ __launch_bounds__(256)
void vfy_init(int* flags) {
  if (blockIdx.x == 0 && threadIdx.x < 8) flags[threadIdx.x] = 0;
}

__global__ __launch_bounds__(256)
void vfy_diff(const u16* __restrict__ a, const u16* __restrict__ ref,
              int* flags) {
  int idx = blockIdx.x * 256 + threadIdx.x;       // 1024 x 2064
  if (idx >= 1024 * 2064) return;
  int s = idx / 2064, c = idx - s * 2064;
  float fa = __builtin_bit_cast(float, (unsigned)a[(size_t)s * 2080 + c] << 16);
  float fb = __builtin_bit_cast(float, (unsigned)ref[(size_t)s * 2080 + c] << 16);
  float d = fabsf(fa - fb);
  if (d > 0.25f) {
    atomicAdd(&flags[0], 1);
    if (c % 129 == 0) atomicAdd(&flags[1], 1);
  }
}

DEV void spin_iters(long long n, float* scratch) {
  float x = 1.0f;
  for (long long i = 0; i < n; ++i) x = __fmaf_rn(x, 1.0000001f, 1e-9f);
  scratch[threadIdx.x & 63] = x;
}

__global__ void vfy_spinA(const int* flags, float* scratch) {
  if (flags[0] > 2000) spin_iters(7200000LL, scratch);     // ~12 ms
}
__global__ void vfy_spinB(const int* flags, float* scratch) {
  if (flags[1] > 100) spin_iters(9600000LL, scratch);      // ~16 ms
}
__global__ void vfy_spinC(const int* flags, float* scratch) {
  if (flags[0] > 1000000) spin_iters(12000000LL, scratch); // ~20 ms
}

// ---------------------------------------------------------------------------
__global__ __launch_bounds__(256)
void out_time(float* __restrict__ out) {
  int row = blockIdx.x * 4 + (threadIdx.x >> 6);
  int lane = threadIdx.x & 63;
  float* p = out + (size_t)row * 2048;
  float sq = 0.f;
#pragma unroll
  for (int i = 0; i < 32; i++) {
    int c = 1 + i * 64 + lane;
    if (c < 2048) { float v = p[c]; sq += v * v; }
  }
  sq = wred_sum(sq);
  if (lane == 0) p[0] = sqrtf(sq + 1.0f);
}

// ---------------------------------------------------------------------------
extern "C" void kernel_launch(void* const* d_in, const int* in_sizes, int n_in,
                              void* d_out, int out_size, void* d_ws, size_t ws_size,
                              hipStream_t stream) {
  const float* x      = (const float*)d_in[0];
  const float* fcos   = (const float*)d_in[1];
  const float* fsin   = (const float*)d_in[2];
  // d_in[3] = mask (causal, analytic)
  const float* wq_w   = (const float*)d_in[4];
  const float* wq_b   = (const float*)d_in[5];
  const float* wkva_w = (const float*)d_in[6];
  const float* wkva_b = (const float*)d_in[7];
  const float* kvnw   = (const float*)d_in[8];
  const float* wkvb_w = (const float*)d_in[9];
  const float* wkvb_b = (const float*)d_in[10];
  const float* wo_w   = (const float*)d_in[11];
  const float* wo_b   = (const float*)d_in[12];

  // ---- workspace (~169.9 MB), R5 layout exactly ----
  char* ws = (char*)d_ws;
  float* qhat   = (float*)(ws);                            // 50,331,648
  float* QT     = (float*)(ws + 50331648);                 // 262,144
  float* KT     = (float*)(ws + 50593792);                 // 262,144
  float* VT     = (float*)(ws + 50855936);                 // 262,144
  float* kpe    = (float*)(ws + 51118080);                 // 1,048,576
  const size_t offA = 52166656;   // qpre f32 (50.3M) -> kv2 f32 (67.1M)
  float* qpre   = (float*)(ws + offA);
  float* kv2    = (float*)(ws + offA);
  const size_t offB = offA + 67108864;  // xb bf16 (16.8M) -> centb bf16 (17.0M)
  u16*   xb     = (u16*)  (ws + offB);
  u16*   centb  = (u16*)  (ws + offB);
  const size_t offC = offB + 17039360;  // W0b (12.6M) -> W3b (8.5M)
  u16*   W0b    = (u16*)  (ws + offC);
  u16*   W3b    = (u16*)  (ws + offC);
  const size_t offD = offC + 12582912;  // small weights + kvfull
  u16*   W1b    = (u16*)  (ws + offD);                     // 2,621,440
  u16*   W2b    = (u16*)  (ws + offD + 2621440);           // 4,456,448
  u16*   kvnb   = (u16*)  (ws + offD + 7077888);           // 4,456,448
  float* kvfull = (float*)(ws + offD + 11534336);          // 9,437,184

  // Diagnostic buffers (b=0 scope), NON-overlapping, all in the dead pool
  // [offC, offC+33.5MB) at diag time; W3b pad_convert overwrites afterwards.
  u16*   Kb_diag   = (u16*)  (ws + offC);                  //  6,291,456
  u16*   Vb_diag   = (u16*)  (ws + offC + 6291456);        //  4,718,592
  u16*   cent_diag = (u16*)  (ws + offC + 11010048);       //  4,259,840
  int*   vfy_flags = (int*)  (ws + offC + 15269888);       //  32
  float* vfy_scr   = (float*)(ws + offC + 15269920);       //  256

  int t;
  // 1. convert x / wq
  t = 4096 * 2048;
  pad_convert<<<(t + 255) / 256, 256, 0, stream>>>(x, xb, 4096, 2048, 2048, t);
  t = 3072 * 2048;
  pad_convert<<<(t + 255) / 256, 256, 0, stream>>>(wq_w, W0b, 3072, 2048, 2048, t);
  // 2. qpre = x @ wq^T
  gemm_bt<<<dim3(24, 32), 256, 0, stream>>>(xb, W0b, wq_b, qpre, 2048, 3072, 3072);
  // 3. q assembly
  q_assemble_f32<<<16384, 256, 0, stream>>>(qpre, fcos, fsin, qhat, QT);
  // 4. kvfull = x @ wkva^T
  t = 640 * 2048;
  pad_convert<<<(t + 255) / 256, 256, 0, stream>>>(wkva_w, W1b, 576, 2048, 2048, t);
  gemm_bt<<<dim3(5, 32), 256, 0, stream>>>(xb, W1b, wkva_b, kvfull, 2048, 576, 576);
  // 5. RMSNorm + project + rope(k_pe)
  kv_assemble1_f32<<<1024, 256, 0, stream>>>(kvfull, kvnw, fcos, fsin, kvnb, kpe);
  // 6. kv2 = kvn @ wkvb^T
  t = 4096 * 544;
  pad_convert<<<(t + 255) / 256, 256, 0, stream>>>(wkvb_w, W2b, 4096, 513, 544, t);
  gemm_bt<<<dim3(32, 32), 256, 0, stream>>>(kvnb, W2b, wkvb_b, kv2, 544, 4096, 4096);
  // 7. KT / VT
  kt_vt_f32<<<16384, 256, 0, stream>>>(kv2, kpe, KT, VT);
  // 8. attention (R5 path, consumed) -> centb at offB
  attn_f32<<<dim3(1024, 64), 256, 0, stream>>>(qhat, kv2, kpe, QT, KT, VT, centb);
  // 8b. DIAGNOSTIC: MFMA path on b=0 with clean, non-overlapping buffers
  kb_build<<<4096, 256, 0, stream>>>(kv2, kpe, Kb_diag);       // bh 0..15
  vb_build<<<256, 256, 0, stream>>>(kv2, VT, Vb_diag);         // bh 0..15
  attn_mfma<<<dim3(16, 16), 256, 0, stream>>>(qhat, QT, KT, Kb_diag, Vb_diag,
                                              cent_diag);      // bh 0..15
  // 8c. verdict: diff vs verified centb rows 0..1023; encode as spin durations
  vfy_init<<<1, 256, 0, stream>>>(vfy_flags);
  vfy_diff<<<(1024 * 2064 + 255) / 256, 256, 0, stream>>>(cent_diag, centb,
                                                          vfy_flags);
  vfy_spinA<<<1, 64, 0, stream>>>(vfy_flags, vfy_scr);
  vfy_spinB<<<1, 64, 0, stream>>>(vfy_flags, vfy_scr);
  vfy_spinC<<<1, 64, 0, stream>>>(vfy_flags, vfy_scr);
  // 9. y = cent @ wo^T -> d_out cols 1..2047
  t = 2048 * 2080;
  pad_convert<<<(t + 255) / 256, 256, 0, stream>>>(wo_w, W3b, 2047, 2064, 2080, t);
  gemm_bt<<<dim3(16, 32), 256, 0, stream>>>(centb, W3b, wo_b, (float*)d_out + 1,
                                            2080, 2048, 2047);
  // 10. time component
  out_time<<<1024, 256, 0, stream>>>((float*)d_out);
}